// Round 13
// baseline (919.342 us; speedup 1.0000x reference)
//
#include <hip/hip_runtime.h>
#include <stdint.h>

#define N_CL 40000
#define NF   20
#define DD   128
#define SS   512
#define NW   625                 // N_CL / 64
#define PARTN (NW * SS)
#define NEGF (-3.0e38f)
#define DISCOUNT 0.995f
#define ECOEF 0.1f

typedef __attribute__((ext_vector_type(4))) float f32x4;
typedef __attribute__((ext_vector_type(16))) float f32x16;
typedef __attribute__((ext_vector_type(8))) short short8;
typedef __attribute__((ext_vector_type(4))) unsigned short us4;

__device__ __forceinline__ float rcpf(float x) { return __builtin_amdgcn_rcpf(x); }
__device__ __forceinline__ float sigm(float x) { return rcpf(1.f + __expf(-x)); }
__device__ __forceinline__ float tanh_fast(float x) { return 1.f - 2.f * rcpf(1.f + __expf(2.f * x)); }
__device__ __forceinline__ unsigned short f2bf(float f) {
    unsigned u = __float_as_uint(f);
    return (unsigned short)((u + 0x7fffu + ((u >> 16) & 1u)) >> 16);   // RNE
}
__device__ __forceinline__ float bf2f(unsigned short s) {
    return __uint_as_float(((unsigned)s) << 16);
}

// ------- pack masks: ballot -> u64 words, TRANSPOSED layout [b][s] -------------
__global__ __launch_bounds__(256) void k_pack(const int* __restrict__ sel,
                                              const int* __restrict__ good,
                                              unsigned long long* __restrict__ selw,
                                              unsigned long long* __restrict__ goodw) {
    int wave = (blockIdx.x * 256 + threadIdx.x) >> 6;   // 0..4999
    int lane = threadIdx.x & 63;
    for (int i = 0; i < 64; ++i) {
        int chunk = wave * 64 + i;                      // 0..319999
        int s = chunk / NW;
        int b = chunk - s * NW;
        int idx = s * N_CL + b * 64 + lane;
        unsigned long long bs = __ballot(sel[idx]  != 0);
        unsigned long long bg = __ballot(good[idx] != 0);
        if (lane == 0) { selw[b * SS + s] = bs; goodw[b * SS + s] = bg; }
    }
}

// ---------------- hidden = relu(features @ W1 + b1) ----------------------------
__global__ __launch_bounds__(256) void k_hidden(const float* __restrict__ feat,
                                                const float* __restrict__ W1,
                                                const float* __restrict__ b1,
                                                float* __restrict__ hidden) {
    int t = threadIdx.x;
    int j = t & 127;
    int r = blockIdx.x * 2 + (t >> 7);
    const float* fr = feat + r * NF;
    float acc = b1[j];
#pragma unroll
    for (int f = 0; f < NF; ++f) acc += fr[f] * W1[f * DD + j];
    hidden[r * DD + j] = fmaxf(acc, 0.f);
}

// ------- emb = hidden @ W2 + b2, emitted as bf16 hi/lo pairs -------------------
#define EMB_FMA(RR) { f32x4 hvv = *(const f32x4*)&hs[rg * 8 + RR][q]; \
    acc##RR += wv0 * hvv.x + wv1 * hvv.y + wv2 * hvv.z + wv3 * hvv.w; }
#define EMB_ST(RR) { f32x4 f = acc##RR + bv; us4 hi, lo; \
    hi[0] = f2bf(f.x); lo[0] = f2bf(f.x - bf2f(hi[0])); \
    hi[1] = f2bf(f.y); lo[1] = f2bf(f.y - bf2f(hi[1])); \
    hi[2] = f2bf(f.z); lo[2] = f2bf(f.z - bf2f(hi[2])); \
    hi[3] = f2bf(f.w); lo[3] = f2bf(f.w - bf2f(hi[3])); \
    int row_ = rbase + rg * 8 + RR; \
    *(us4*)&emb_hi[row_ * DD + c4 * 4] = hi; \
    *(us4*)&emb_lo[row_ * DD + c4 * 4] = lo; }

__global__ __launch_bounds__(256) void k_emb(const float* __restrict__ hidden,
                                             const float* __restrict__ W2,
                                             const float* __restrict__ b2,
                                             unsigned short* __restrict__ emb_hi,
                                             unsigned short* __restrict__ emb_lo) {
    __shared__ float hs[64][132];                     // +4 pad, 33.8 KB
    int t = threadIdx.x;
    int rbase = blockIdx.x * 64;
#pragma unroll
    for (int i = t; i < 2048; i += 256) {             // stage 64x128 hidden tile
        int r = i >> 5, k4 = i & 31;
        *(f32x4*)&hs[r][k4 * 4] = *(const f32x4*)&hidden[(rbase + r) * DD + k4 * 4];
    }
    __syncthreads();
    int c4 = t & 31, rg = t >> 5;
    f32x4 acc0{0,0,0,0}, acc1{0,0,0,0}, acc2{0,0,0,0}, acc3{0,0,0,0},
          acc4{0,0,0,0}, acc5{0,0,0,0}, acc6{0,0,0,0}, acc7{0,0,0,0};
    for (int q = 0; q < DD; q += 4) {
        f32x4 wv0 = *(const f32x4*)&W2[(q + 0) * DD + c4 * 4];
        f32x4 wv1 = *(const f32x4*)&W2[(q + 1) * DD + c4 * 4];
        f32x4 wv2 = *(const f32x4*)&W2[(q + 2) * DD + c4 * 4];
        f32x4 wv3 = *(const f32x4*)&W2[(q + 3) * DD + c4 * 4];
        EMB_FMA(0) EMB_FMA(1) EMB_FMA(2) EMB_FMA(3)
        EMB_FMA(4) EMB_FMA(5) EMB_FMA(6) EMB_FMA(7)
    }
    f32x4 bv = *(const f32x4*)&b2[c4 * 4];
    EMB_ST(0) EMB_ST(1) EMB_ST(2) EMB_ST(3)
    EMB_ST(4) EMB_ST(5) EMB_ST(6) EMB_ST(7)
}

// ---- P2[s][pos][g] = bih[j]+bhh[j]+Wih[j].emb[sel_idx[s]],  j=g*128+pos ------
__global__ __launch_bounds__(256) void k_pgemm(const unsigned short* __restrict__ emb_hi,
                                               const unsigned short* __restrict__ emb_lo,
                                               const int* __restrict__ sel_idx,
                                               const float* __restrict__ Wih,
                                               const float* __restrict__ bih,
                                               const float* __restrict__ bhh,
                                               float* __restrict__ P2) {
    __shared__ __align__(16) float x8[8][DD];
    int t = threadIdx.x;
    int sb = blockIdx.x * 8;
    for (int i = t; i < 8 * DD; i += 256) {
        int sl = i >> 7, k = i & 127;
        int idx = sel_idx[sb + sl] * DD + k;
        x8[sl][k] = bf2f(emb_hi[idx]) + bf2f(emb_lo[idx]);
    }
    __syncthreads();
    for (int jj = t; jj < 512; jj += 256) {
        float base = bih[jj] + bhh[jj];
        float acc[8];
#pragma unroll
        for (int s8 = 0; s8 < 8; ++s8) acc[s8] = base;
        const float4* wr = (const float4*)(Wih + jj * DD);
        for (int q = 0; q < 32; ++q) {
            float4 w4 = wr[q];
#pragma unroll
            for (int s8 = 0; s8 < 8; ++s8) {
                const float4* xs = (const float4*)&x8[s8][0];
                float4 xv = xs[q];
                acc[s8] += w4.x * xv.x + w4.y * xv.y + w4.z * xv.z + w4.w * xv.w;
            }
        }
        int pos = jj & 127, g = jj >> 7;
        for (int s8 = 0; s8 < 8; ++s8) P2[(sb + s8) * 512 + pos * 4 + g] = acc[s8];
    }
}

// ------- sequential LSTM scan: eighth-K octets, shfl tree, ONE barrier ---------
// 512 threads = 8 waves. Thread t: octet o=t>>3, lane j=t&7. Owns the 8 rows
// {i,f,g,o} x {2o, 2o+1} over K-eighth j (16 floats). After matvec, a 3-round
// specialized shfl tree (xor 1/2/4, payload 4->2->1) leaves lane j with the
// full-K sum of gate (j>>1), position 2o+(j&1). Per-lane nonlin, 3-shfl gate
// exchange, replicated c-update. No psum LDS; ONE __syncthreads per step.
// h_sh is stored in padded eighths (20 floats each) so the per-lane-eighth
// b128 reads are conflict-free 8-way multicast.
#define LOADW(NAME, ROW) \
    const f32x4* NAME##p = (const f32x4*)(Whh + (ROW) * DD + j8 * 16); \
    f32x4 NAME##0 = NAME##p[0], NAME##1 = NAME##p[1], \
          NAME##2 = NAME##p[2], NAME##3 = NAME##p[3];

#define MACI(I) { f32x4 hv = hp[I]; \
    aa += wa##I * hv; ab += wb##I * hv; ac += wc##I * hv; ad += wd##I * hv; \
    ae += we##I * hv; af += wf##I * hv; ag2 += wg##I * hv; ah += wh##I * hv; }

__global__ __launch_bounds__(512, 1) void k_lstm(const float* __restrict__ Whh,
                                                 const float* __restrict__ P2,
                                                 const float* __restrict__ init_h,
                                                 const float* __restrict__ init_c,
                                                 unsigned short* __restrict__ Hhi,
                                                 unsigned short* __restrict__ Hlo) {
    __shared__ __align__(16) float pbuf[2][4096];   // 32 KB: two 8-step P chunks
    __shared__ __align__(16) float h_sh[2][160];    // 8 eighths x (16 + 4 pad)
    int t = threadIdx.x, w = t >> 6, l = t & 63;
    int j8 = t & 7, oct = t >> 3;
    int pos = 2 * oct + (t & 1);                    // this lane's position
    int gt = (t >> 1) & 3;                          // this lane's gate type

    int p0 = 2 * oct, p1 = p0 + 1;
    LOADW(wa, p0)        LOADW(wb, p1)
    LOADW(wc, 128 + p0)  LOADW(wd, 128 + p1)
    LOADW(we, 256 + p0)  LOADW(wf, 256 + p1)
    LOADW(wg, 384 + p0)  LOADW(wh, 384 + p1)

    auto issue = [&](int cidx, int bufi) {          // stage one 8-step P chunk
        if (cidx >= SS / 8) return;
        const float* src = P2 + cidx * 4096 + w * 512 + l * 4;
        float* dst = &pbuf[bufi][w * 512];
#pragma unroll
        for (int i = 0; i < 2; ++i) {
            __builtin_amdgcn_global_load_lds(
                (const __attribute__((address_space(1))) void*)(src + i * 256),
                (__attribute__((address_space(3))) void*)(dst + i * 256),
                16, 0, 0);
        }
    };

    float c = init_c[pos];                          // 4 replicas per position
    if (t < DD) {
        float f = init_h[t];
        h_sh[0][(t >> 4) * 20 + (t & 15)] = f;      // padded-eighth layout
        unsigned short hi = f2bf(f);
        Hhi[t] = hi; Hlo[t] = f2bf(f - bf2f(hi));
    }
    issue(0, 0);
    __syncthreads();

    // nonlinearity constants for THIS lane's gate: gt==2 -> tanh, else sigmoid
    float na = (gt == 2) ? 2.f : -1.f;
    float nk = (gt == 2) ? -2.f : 1.f;
    float nb = (gt == 2) ? 1.f : 0.f;
    bool q1 = (t & 2) != 0, q2 = (t & 4) != 0;
    float hbuf[8];
    for (int s = 0; s < SS; ++s) {
        int cur = s & 1, nxt = cur ^ 1;
        int buf = (s >> 3) & 1;
        if ((s & 7) == 0) issue((s >> 3) + 1, buf ^ 1);
        const f32x4* hp = (const f32x4*)&h_sh[cur][j8 * 20];   // 8-way multicast
        f32x4 aa{0,0,0,0}, ab{0,0,0,0}, ac{0,0,0,0}, ad{0,0,0,0},
              ae{0,0,0,0}, af{0,0,0,0}, ag2{0,0,0,0}, ah{0,0,0,0};
        MACI(0) MACI(1) MACI(2) MACI(3)
        // horizontal sums -> gates of p0 (a_lo) and p1 (a_hi)
        f32x4 a_lo, a_hi;
        a_lo.x = (aa.x + aa.y) + (aa.z + aa.w);
        a_lo.y = (ac.x + ac.y) + (ac.z + ac.w);
        a_lo.z = (ae.x + ae.y) + (ae.z + ae.w);
        a_lo.w = (ag2.x + ag2.y) + (ag2.z + ag2.w);
        a_hi.x = (ab.x + ab.y) + (ab.z + ab.w);
        a_hi.y = (ad.x + ad.y) + (ad.z + ad.w);
        a_hi.z = (af.x + af.y) + (af.z + af.w);
        a_hi.w = (ah.x + ah.y) + (ah.z + ah.w);
        // round 1 (xor 1): keep my position's 4 gates
        bool b0 = (t & 1) != 0;
        f32x4 mine = b0 ? a_hi : a_lo;
        f32x4 othr = b0 ? a_lo : a_hi;
        f32x4 v4;
        v4.x = mine.x + __shfl_xor(othr.x, 1);
        v4.y = mine.y + __shfl_xor(othr.y, 1);
        v4.z = mine.z + __shfl_xor(othr.z, 1);
        v4.w = mine.w + __shfl_xor(othr.w, 1);
        // round 2 (xor 2): keep gate pair (bit q1)
        float m2x = q1 ? v4.z : v4.x, m2y = q1 ? v4.w : v4.y;
        float o2x = q1 ? v4.x : v4.z, o2y = q1 ? v4.y : v4.w;
        float v2x = m2x + __shfl_xor(o2x, 2);
        float v2y = m2y + __shfl_xor(o2y, 2);
        // round 3 (xor 4): keep my gate (bit q2)
        float m1 = q2 ? v2y : v2x, o1 = q2 ? v2x : v2y;
        float gsum = m1 + __shfl_xor(o1, 4);
        gsum += pbuf[buf][(s & 7) * 512 + pos * 4 + gt];
        // per-lane nonlinearity, then 3-shfl gate exchange
        float y = fmaf(rcpf(1.f + __expf(na * gsum)), nk, nb);
        float t2 = __shfl_xor(y, 2);
        float t4 = __shfl_xor(y, 4);
        float t6 = __shfl_xor(t2, 4);
        float ii = q2 ? (q1 ? t6 : t4) : (q1 ? t2 : y);
        float ff = q2 ? (q1 ? t4 : t6) : (q1 ? y  : t2);
        float tg = q2 ? (q1 ? t2 : y)  : (q1 ? t6 : t4);
        float oo = q2 ? (q1 ? y  : t2) : (q1 ? t4 : t6);
        c = ff * c + ii * tg;
        float hn = oo * tanh_fast(c);
        if (j8 < 2) {
            h_sh[nxt][(pos >> 4) * 20 + (pos & 15)] = hn;
            if (s < SS - 1) {
                hbuf[s & 7] = hn;
                if ((s & 7) == 7) {                 // batched H store, 1/8 steps
#pragma unroll
                    for (int k2 = 0; k2 < 8; ++k2) {
                        float f = hbuf[k2];
                        unsigned short hi = f2bf(f);
                        Hhi[(s - 6 + k2) * DD + pos] = hi;
                        Hlo[(s - 6 + k2) * DD + pos] = f2bf(f - bf2f(hi));
                    }
                }
            }
        }
        __syncthreads();                            // the ONE barrier per step
    }
    if (j8 < 2) {                                   // steps 504..510 -> H[505..511]
#pragma unroll
        for (int k2 = 0; k2 < 7; ++k2) {
            float f = hbuf[k2];
            unsigned short hi = f2bf(f);
            Hhi[(505 + k2) * DD + pos] = hi;
            Hlo[(505 + k2) * DD + pos] = f2bf(f - bf2f(hi));
        }
    }
}

// ------- phase C: MFMA GEMM logits + masked-softmax epilogue -------------------
// Grid 2500: b = blk>>2 (64-row tile), (blk&3, wave) -> 32-step group.
__global__ __launch_bounds__(256, 1) void k_logits(
        const unsigned short* __restrict__ emb_hi,
        const unsigned short* __restrict__ emb_lo,
        const unsigned short* __restrict__ Hhi,
        const unsigned short* __restrict__ Hlo,
        const unsigned long long* __restrict__ selw,
        const unsigned long long* __restrict__ goodw,
        float* __restrict__ part) {
    int blk = blockIdx.x;
    int b = blk >> 2;
    int t = threadIdx.x, wv = t >> 6, l = t & 63;
    int s0 = (blk & 3) * 128 + wv * 32;
    int ln = l & 31, lh = l >> 5;
    int rb = b * 64;
    const short8* A0h = (const short8*)(emb_hi + (rb + ln) * DD + lh * 8);
    const short8* A0l = (const short8*)(emb_lo + (rb + ln) * DD + lh * 8);
    const short8* A1h = (const short8*)(emb_hi + (rb + 32 + ln) * DD + lh * 8);
    const short8* A1l = (const short8*)(emb_lo + (rb + 32 + ln) * DD + lh * 8);
    const short8* Bhp = (const short8*)(Hhi + (s0 + ln) * DD + lh * 8);
    const short8* Blp = (const short8*)(Hlo + (s0 + ln) * DD + lh * 8);
    f32x16 acc0, acc1;
#pragma unroll
    for (int r = 0; r < 16; ++r) { acc0[r] = 0.f; acc1[r] = 0.f; }
#pragma unroll
    for (int kc = 0; kc < 8; ++kc) {               // K = 8 x 16
        short8 a0h = A0h[kc * 2], a0l = A0l[kc * 2];
        short8 a1h = A1h[kc * 2], a1l = A1l[kc * 2];
        short8 bh = Bhp[kc * 2], bl = Blp[kc * 2];
        acc0 = __builtin_amdgcn_mfma_f32_32x32x16_bf16(a0h, bh, acc0, 0, 0, 0);
        acc0 = __builtin_amdgcn_mfma_f32_32x32x16_bf16(a0l, bh, acc0, 0, 0, 0);
        acc0 = __builtin_amdgcn_mfma_f32_32x32x16_bf16(a0h, bl, acc0, 0, 0, 0);
        acc1 = __builtin_amdgcn_mfma_f32_32x32x16_bf16(a1h, bh, acc1, 0, 0, 0);
        acc1 = __builtin_amdgcn_mfma_f32_32x32x16_bf16(a1l, bh, acc1, 0, 0, 0);
        acc1 = __builtin_amdgcn_mfma_f32_32x32x16_bf16(a1h, bl, acc1, 0, 0, 0);
    }
    int s = s0 + ln;
    unsigned long long sw = selw[b * SS + s];      // coalesced, [b][s] layout
    unsigned long long gw = goodw[b * SS + s];
    float m = NEGF;
#pragma unroll
    for (int r = 0; r < 16; ++r) {
        int row = (r & 3) + 8 * (r >> 2) + 4 * lh;
        float v0 = acc0[r], v1 = acc1[r];
        m = fmaxf(m, ((sw >> row) & 1ull) ? v0 : NEGF);
        m = fmaxf(m, ((sw >> (row + 32)) & 1ull) ? v1 : NEGF);
    }
    m = fmaxf(m, __shfl_xor(m, 32));
    float se = 0.f, sl = 0.f, slg = 0.f;
#pragma unroll
    for (int r = 0; r < 16; ++r) {
        int row = (r & 3) + 8 * (r >> 2) + 4 * lh;
        float v0 = acc0[r], v1 = acc1[r];
        float e0 = ((sw >> row) & 1ull) ? __expf(v0 - m) : 0.f;
        float e1 = ((sw >> (row + 32)) & 1ull) ? __expf(v1 - m) : 0.f;
        se += e0 + e1;
        sl += e0 * v0 + e1 * v1;
        slg += (((gw >> row) & 1ull) ? v0 : 0.f)
             + (((gw >> (row + 32)) & 1ull) ? v1 : 0.f);
    }
    se += __shfl_xor(se, 32);
    sl += __shfl_xor(sl, 32);
    slg += __shfl_xor(slg, 32);
    if (lh == 0) {
        int o = s * NW + b;                        // TRANSPOSED part: [s][b]
        part[0 * PARTN + o] = m;
        part[1 * PARTN + o] = se;
        part[2 * PARTN + o] = sl;
        part[3 * PARTN + o] = slg;
        part[4 * PARTN + o] = (float)__popcll(sw);
        part[5 * PARTN + o] = (float)__popcll(gw);
    }
}

// ------- per-step merge of 625 block partials (coalesced [s][b] reads) ---------
__global__ __launch_bounds__(64) void k_reduce(const float* __restrict__ part,
                                               float* __restrict__ Aout,
                                               float* __restrict__ Bout,
                                               float* __restrict__ actout) {
    int s = blockIdx.x;
    int t = threadIdx.x;     // 64 threads, one wave
    float m = NEGF, se = 0.f, sl = 0.f, slg = 0.f, np = 0.f, ng = 0.f;
    for (int b = t; b < NW; b += 64) {
        int o = s * NW + b;                        // lanes consecutive
        float m2  = part[0 * PARTN + o];
        float se2 = part[1 * PARTN + o];
        float sl2 = part[2 * PARTN + o];
        slg += part[3 * PARTN + o];
        np  += part[4 * PARTN + o];
        ng  += part[5 * PARTN + o];
        float nm = fmaxf(m, m2);
        float a = __expf(m - nm), a2 = __expf(m2 - nm);
        se = se * a + se2 * a2;
        sl = sl * a + sl2 * a2;
        m = nm;
    }
    for (int off = 32; off > 0; off >>= 1) {
        float m2  = __shfl_xor(m, off);
        float se2 = __shfl_xor(se, off);
        float sl2 = __shfl_xor(sl, off);
        slg += __shfl_xor(slg, off);
        np  += __shfl_xor(np, off);
        ng  += __shfl_xor(ng, off);
        float nm = fmaxf(m, m2);
        float a = __expf(m - nm), a2 = __expf(m2 - nm);
        se = se * a + se2 * a2;
        sl = sl * a + sl2 * a2;
        m = nm;
    }
    if (t == 0) {
        float lse = m + logf(se);
        float nbad = np - ng;
        int active = (ng > 0.5f) && (nbad > 0.5f);
        float ce = (ng * lse - slg) / fmaxf(ng, 1.f);
        float A = (nbad / fmaxf(np, 1.f)) * ce;
        float minus_ent = sl / se - lse;
        float B = ECOEF * (minus_ent / logf(fmaxf(np, 2.0f)));
        Aout[s] = A; Bout[s] = B; actout[s] = active ? 1.f : 0.f;
    }
}

// ---------------- exact sequential discount prefix + final sum -----------------
__global__ __launch_bounds__(64) void k_final(const float* __restrict__ A,
                                              const float* __restrict__ B,
                                              const float* __restrict__ act,
                                              float* __restrict__ out) {
    int lane = threadIdx.x;
    float loss = 0.f;
    int base = 0;
    for (int ch = 0; ch < 8; ++ch) {
        int s = ch * 64 + lane;
        bool a = act[s] > 0.5f;
        unsigned long long bal = __ballot(a);
        unsigned long long ltmask = (lane == 0) ? 0ull : (~0ull >> (64 - lane));
        int pre = __popcll(bal & ltmask);
        if (a) {
            float f = powf(DISCOUNT, (float)(base + pre));
            loss += f * A[s] + B[s];
        }
        base += __popcll(bal);
    }
    for (int off = 32; off > 0; off >>= 1) loss += __shfl_xor(loss, off);
    if (lane == 0) out[0] = loss / fmaxf((float)base, 1.f);
}

extern "C" void kernel_launch(void* const* d_in, const int* in_sizes, int n_in,
                              void* d_out, int out_size, void* d_ws, size_t ws_size,
                              hipStream_t stream) {
    (void)in_sizes; (void)n_in; (void)out_size; (void)ws_size;
    const float* feat    = (const float*)d_in[0];
    const int*   sel     = (const int*)d_in[1];
    const int*   good    = (const int*)d_in[2];
    const int*   sel_idx = (const int*)d_in[3];
    const float* W1      = (const float*)d_in[4];
    const float* b1      = (const float*)d_in[5];
    const float* W2      = (const float*)d_in[6];
    const float* b2      = (const float*)d_in[7];
    const float* init_h  = (const float*)d_in[8];
    const float* init_c  = (const float*)d_in[9];
    const float* Wih     = (const float*)d_in[10];
    const float* Whh     = (const float*)d_in[11];
    const float* bih     = (const float*)d_in[12];
    const float* bhh     = (const float*)d_in[13];
    float* out = (float*)d_out;
    char* ws = (char*)d_ws;

    float*          hidden = (float*)(ws + 0);                    // 20,480,000 B
    unsigned short* emb_hi = (unsigned short*)(ws + 20480000);    // 10,240,000 B
    unsigned short* emb_lo = (unsigned short*)(ws + 30720000);    // 10,240,000 B
    float*          P2     = (float*)(ws + 40960000);             //  1,048,576 B
    unsigned short* Hhi    = (unsigned short*)(ws + 42008576);    //    131,072 B
    unsigned short* Hlo    = (unsigned short*)(ws + 42139648);    //    131,072 B
    unsigned long long* selw  = (unsigned long long*)(ws + 42270720);  // 2,560,000 B
    unsigned long long* goodw = (unsigned long long*)(ws + 44830720);  // 2,560,000 B
    float*          part   = (float*)(ws + 47390720);             //  7,680,000 B
    float*          Aarr   = (float*)(ws + 55070720);             //      2,048 B
    float*          Barr   = (float*)(ws + 55072768);             //      2,048 B
    float*          actarr = (float*)(ws + 55074816);             //      2,048 B

    k_pack  <<<1250, 256, 0, stream>>>(sel, good, selw, goodw);
    k_hidden<<<N_CL / 2, 256, 0, stream>>>(feat, W1, b1, hidden);
    k_emb   <<<NW, 256, 0, stream>>>(hidden, W2, b2, emb_hi, emb_lo);
    k_pgemm <<<64, 256, 0, stream>>>(emb_hi, emb_lo, sel_idx, Wih, bih, bhh, P2);
    k_lstm  <<<1, 512, 0, stream>>>(Whh, P2, init_h, init_c, Hhi, Hlo);
    k_logits<<<NW * 4, 256, 0, stream>>>(emb_hi, emb_lo, Hhi, Hlo, selw, goodw, part);
    k_reduce<<<SS, 64, 0, stream>>>(part, Aarr, Barr, actarr);
    k_final <<<1, 64, 0, stream>>>(Aarr, Barr, actarr, out);
}

// Round 15
// 833.636 us; speedup vs baseline: 1.1028x; 1.1028x over previous
//
#include <hip/hip_runtime.h>
#include <stdint.h>

#define N_CL 40000
#define NF   20
#define DD   128
#define SS   512
#define NW   625                 // N_CL / 64
#define PARTN (NW * SS)
#define NEGF (-3.0e38f)
#define DISCOUNT 0.995f
#define ECOEF 0.1f

typedef __attribute__((ext_vector_type(4))) float f32x4;
typedef __attribute__((ext_vector_type(16))) float f32x16;
typedef __attribute__((ext_vector_type(8))) short short8;
typedef __attribute__((ext_vector_type(4))) unsigned short us4;

__device__ __forceinline__ float rcpf(float x) { return __builtin_amdgcn_rcpf(x); }
__device__ __forceinline__ float sigm(float x) { return rcpf(1.f + __expf(-x)); }
__device__ __forceinline__ float tanh_fast(float x) { return 1.f - 2.f * rcpf(1.f + __expf(2.f * x)); }
__device__ __forceinline__ unsigned short f2bf(float f) {
    unsigned u = __float_as_uint(f);
    return (unsigned short)((u + 0x7fffu + ((u >> 16) & 1u)) >> 16);   // RNE
}
__device__ __forceinline__ float bf2f(unsigned short s) {
    return __uint_as_float(((unsigned)s) << 16);
}

// ------- pack masks: ballot -> u64 words, TRANSPOSED layout [b][s] -------------
__global__ __launch_bounds__(256) void k_pack(const int* __restrict__ sel,
                                              const int* __restrict__ good,
                                              unsigned long long* __restrict__ selw,
                                              unsigned long long* __restrict__ goodw) {
    int wave = (blockIdx.x * 256 + threadIdx.x) >> 6;   // 0..4999
    int lane = threadIdx.x & 63;
    for (int i = 0; i < 64; ++i) {
        int chunk = wave * 64 + i;                      // 0..319999
        int s = chunk / NW;
        int b = chunk - s * NW;
        int idx = s * N_CL + b * 64 + lane;
        unsigned long long bs = __ballot(sel[idx]  != 0);
        unsigned long long bg = __ballot(good[idx] != 0);
        if (lane == 0) { selw[b * SS + s] = bs; goodw[b * SS + s] = bg; }
    }
}

// ------- FUSED hidden+emb: emb = relu(feat@W1+b1)@W2+b2, bf16 hi/lo out --------
#define EMB_FMA(RR) { f32x4 hvv = *(const f32x4*)&hs[rg * 8 + RR][q]; \
    acc##RR += wv0 * hvv.x + wv1 * hvv.y + wv2 * hvv.z + wv3 * hvv.w; }
#define EMB_ST(RR) { f32x4 f = acc##RR + bv; us4 hi, lo; \
    hi[0] = f2bf(f.x); lo[0] = f2bf(f.x - bf2f(hi[0])); \
    hi[1] = f2bf(f.y); lo[1] = f2bf(f.y - bf2f(hi[1])); \
    hi[2] = f2bf(f.z); lo[2] = f2bf(f.z - bf2f(hi[2])); \
    hi[3] = f2bf(f.w); lo[3] = f2bf(f.w - bf2f(hi[3])); \
    int row_ = rbase + rg * 8 + RR; \
    *(us4*)&emb_hi[row_ * DD + c4 * 4] = hi; \
    *(us4*)&emb_lo[row_ * DD + c4 * 4] = lo; }

__global__ __launch_bounds__(256) void k_emb(const float* __restrict__ feat,
                                             const float* __restrict__ W1,
                                             const float* __restrict__ b1,
                                             const float* __restrict__ W2,
                                             const float* __restrict__ b2,
                                             unsigned short* __restrict__ emb_hi,
                                             unsigned short* __restrict__ emb_lo) {
    __shared__ float fs[64][NF];                      // 5.1 KB feat tile
    __shared__ float hs[64][132];                     // +4 pad, 33.8 KB
    int t = threadIdx.x;
    int rbase = blockIdx.x * 64;
    for (int i = t; i < 64 * NF; i += 256)
        fs[i / NF][i % NF] = feat[rbase * NF + i];
    __syncthreads();
    {   // hidden tile: 64 rows x 128 cols = 8192 elems, 32 per thread.
        // threads 0-127 (t>>7==0): even rows; 128-255: odd rows. k=0..31.
        int c = t & 127;
        float bb = b1[c];
#pragma unroll
        for (int k = 0; k < 32; ++k) {
            int r = (t >> 7) + 2 * k;
            float acc = bb;
#pragma unroll
            for (int f = 0; f < NF; ++f) acc += fs[r][f] * W1[f * DD + c];
            hs[r][c] = fmaxf(acc, 0.f);
        }
    }
    __syncthreads();
    int c4 = t & 31, rg = t >> 5;
    f32x4 acc0{0,0,0,0}, acc1{0,0,0,0}, acc2{0,0,0,0}, acc3{0,0,0,0},
          acc4{0,0,0,0}, acc5{0,0,0,0}, acc6{0,0,0,0}, acc7{0,0,0,0};
    for (int q = 0; q < DD; q += 4) {
        f32x4 wv0 = *(const f32x4*)&W2[(q + 0) * DD + c4 * 4];
        f32x4 wv1 = *(const f32x4*)&W2[(q + 1) * DD + c4 * 4];
        f32x4 wv2 = *(const f32x4*)&W2[(q + 2) * DD + c4 * 4];
        f32x4 wv3 = *(const f32x4*)&W2[(q + 3) * DD + c4 * 4];
        EMB_FMA(0) EMB_FMA(1) EMB_FMA(2) EMB_FMA(3)
        EMB_FMA(4) EMB_FMA(5) EMB_FMA(6) EMB_FMA(7)
    }
    f32x4 bv = *(const f32x4*)&b2[c4 * 4];
    EMB_ST(0) EMB_ST(1) EMB_ST(2) EMB_ST(3)
    EMB_ST(4) EMB_ST(5) EMB_ST(6) EMB_ST(7)
}

// ---- P2[s][pos][g] = bih[j]+bhh[j]+Wih[j].emb[sel_idx[s]],  j=g*128+pos ------
__global__ __launch_bounds__(256) void k_pgemm(const unsigned short* __restrict__ emb_hi,
                                               const unsigned short* __restrict__ emb_lo,
                                               const int* __restrict__ sel_idx,
                                               const float* __restrict__ Wih,
                                               const float* __restrict__ bih,
                                               const float* __restrict__ bhh,
                                               float* __restrict__ P2) {
    __shared__ __align__(16) float x8[8][DD];
    int t = threadIdx.x;
    int sb = blockIdx.x * 8;
    for (int i = t; i < 8 * DD; i += 256) {
        int sl = i >> 7, k = i & 127;
        int idx = sel_idx[sb + sl] * DD + k;
        x8[sl][k] = bf2f(emb_hi[idx]) + bf2f(emb_lo[idx]);
    }
    __syncthreads();
    for (int jj = t; jj < 512; jj += 256) {
        float base = bih[jj] + bhh[jj];
        float acc[8];
#pragma unroll
        for (int s8 = 0; s8 < 8; ++s8) acc[s8] = base;
        const float4* wr = (const float4*)(Wih + jj * DD);
        for (int q = 0; q < 32; ++q) {
            float4 w4 = wr[q];
#pragma unroll
            for (int s8 = 0; s8 < 8; ++s8) {
                const float4* xs = (const float4*)&x8[s8][0];
                float4 xv = xs[q];
                acc[s8] += w4.x * xv.x + w4.y * xv.y + w4.z * xv.z + w4.w * xv.w;
            }
        }
        int pos = jj & 127, g = jj >> 7;
        for (int s8 = 0; s8 < 8; ++s8) P2[(sb + s8) * 512 + pos * 4 + g] = acc[s8];
    }
}

// ------- sequential LSTM scan: quarter-K split (r12) + wave-7 H-store offload --
#define MQ(Q) { f32x4 hv = hp[Q]; \
    a0 += w0##Q * hv; a1 += w1##Q * hv; a2 += w2##Q * hv; a3 += w3##Q * hv; }

__global__ __launch_bounds__(512, 1) void k_lstm(const float* __restrict__ Whh,
                                                 const float* __restrict__ P2,
                                                 const float* __restrict__ init_h,
                                                 const float* __restrict__ init_c,
                                                 unsigned short* __restrict__ Hhi,
                                                 unsigned short* __restrict__ Hlo) {
    __shared__ __align__(16) float pbuf[2][4096];   // 32 KB: two 8-step P chunks
    __shared__ __align__(16) float psum[4][512];    // [kq][row]
    __shared__ __align__(16) float h_sh[2][DD];     // double-buffered hidden
    int t = threadIdx.x, w = t >> 6, l = t & 63;
    int kq = w & 3, gh = w >> 2;
    int gbase = gh * 256 + l * 4;

    const f32x4* wr0 = (const f32x4*)(Whh + (gbase + 0) * DD + kq * 32);
    const f32x4* wr1 = (const f32x4*)(Whh + (gbase + 1) * DD + kq * 32);
    const f32x4* wr2 = (const f32x4*)(Whh + (gbase + 2) * DD + kq * 32);
    const f32x4* wr3 = (const f32x4*)(Whh + (gbase + 3) * DD + kq * 32);
    f32x4 w00 = wr0[0], w01 = wr0[1], w02 = wr0[2], w03 = wr0[3],
          w04 = wr0[4], w05 = wr0[5], w06 = wr0[6], w07 = wr0[7];
    f32x4 w10 = wr1[0], w11 = wr1[1], w12 = wr1[2], w13 = wr1[3],
          w14 = wr1[4], w15 = wr1[5], w16 = wr1[6], w17 = wr1[7];
    f32x4 w20 = wr2[0], w21 = wr2[1], w22 = wr2[2], w23 = wr2[3],
          w24 = wr2[4], w25 = wr2[5], w26 = wr2[6], w27 = wr2[7];
    f32x4 w30 = wr3[0], w31 = wr3[1], w32 = wr3[2], w33 = wr3[3],
          w34 = wr3[4], w35 = wr3[5], w36 = wr3[6], w37 = wr3[7];

    auto issue = [&](int cidx, int bufi) {          // stage one 8-step P chunk
        if (cidx >= SS / 8) return;
        const float* src = P2 + cidx * 4096 + w * 512 + l * 4;
        float* dst = &pbuf[bufi][w * 512];
#pragma unroll
        for (int i = 0; i < 2; ++i) {
            __builtin_amdgcn_global_load_lds(
                (const __attribute__((address_space(1))) void*)(src + i * 256),
                (__attribute__((address_space(3))) void*)(dst + i * 256),
                16, 0, 0);
        }
    };

    float c = 0.f;
    if (t < DD) { h_sh[0][t] = init_h[t]; c = init_c[t]; }
    issue(0, 0);
    __syncthreads();

    for (int s = 0; s < SS; ++s) {
        int cur = s & 1, nxt = cur ^ 1;
        int buf = (s >> 3) & 1;
        if ((s & 7) == 0) issue((s >> 3) + 1, buf ^ 1);
        if (w == 7) {                               // H[s] store, off critical path
            float f0 = h_sh[cur][l], f1 = h_sh[cur][64 + l];
            unsigned short h0 = f2bf(f0), h1 = f2bf(f1);
            Hhi[s * DD + l] = h0;
            Hhi[s * DD + 64 + l] = h1;
            Hlo[s * DD + l] = f2bf(f0 - bf2f(h0));
            Hlo[s * DD + 64 + l] = f2bf(f1 - bf2f(h1));
        }
        const f32x4* hp = (const f32x4*)&h_sh[cur][kq * 32];  // wave-uniform bcast
        f32x4 a0{0,0,0,0}, a1{0,0,0,0}, a2{0,0,0,0}, a3{0,0,0,0};
        MQ(0) MQ(1) MQ(2) MQ(3) MQ(4) MQ(5) MQ(6) MQ(7)
        f32x4 ps;
        ps.x = (a0.x + a0.y) + (a0.z + a0.w);
        ps.y = (a1.x + a1.y) + (a1.z + a1.w);
        ps.z = (a2.x + a2.y) + (a2.z + a2.w);
        ps.w = (a3.x + a3.y) + (a3.z + a3.w);
        *(f32x4*)&psum[kq][gbase] = ps;             // stride-16B, conflict-free
        __syncthreads();
        if (t < DD) {
            float4 pv = *(const float4*)&pbuf[buf][(s & 7) * 512 + t * 4];
            float gi = ((psum[0][t]       + psum[1][t])       + (psum[2][t]       + psum[3][t]))       + pv.x;
            float gf = ((psum[0][128 + t] + psum[1][128 + t]) + (psum[2][128 + t] + psum[3][128 + t])) + pv.y;
            float gg = ((psum[0][256 + t] + psum[1][256 + t]) + (psum[2][256 + t] + psum[3][256 + t])) + pv.z;
            float go = ((psum[0][384 + t] + psum[1][384 + t]) + (psum[2][384 + t] + psum[3][384 + t])) + pv.w;
            float ii = sigm(gi), ff = sigm(gf), tg = tanh_fast(gg), oo = sigm(go);
            c = ff * c + ii * tg;
            h_sh[nxt][t] = oo * tanh_fast(c);
        }
        __syncthreads();
    }
}

// ------- phase C: MFMA GEMM logits, SINGLE PASS over all 512 steps -------------
__global__ __launch_bounds__(256, 1) void k_logits(
        const unsigned short* __restrict__ emb_hi,
        const unsigned short* __restrict__ emb_lo,
        const unsigned short* __restrict__ Hhi,
        const unsigned short* __restrict__ Hlo,
        const unsigned long long* __restrict__ selw,
        const unsigned long long* __restrict__ goodw,
        float* __restrict__ part) {
    int b = blockIdx.x;
    int t = threadIdx.x, wv = t >> 6, l = t & 63;
    int ln = l & 31, lh = l >> 5;
    int rb = b * 64;
    const short8* A0h = (const short8*)(emb_hi + (rb + ln) * DD + lh * 8);
    const short8* A0l = (const short8*)(emb_lo + (rb + ln) * DD + lh * 8);
    const short8* A1h = (const short8*)(emb_hi + (rb + 32 + ln) * DD + lh * 8);
    const short8* A1l = (const short8*)(emb_lo + (rb + 32 + ln) * DD + lh * 8);
    for (int sg = 0; sg < 4; ++sg) {
        int s0 = sg * 128 + wv * 32;
        const short8* Bhp = (const short8*)(Hhi + (s0 + ln) * DD + lh * 8);
        const short8* Blp = (const short8*)(Hlo + (s0 + ln) * DD + lh * 8);
        f32x16 acc0, acc1;
#pragma unroll
        for (int r = 0; r < 16; ++r) { acc0[r] = 0.f; acc1[r] = 0.f; }
#pragma unroll
        for (int kc = 0; kc < 8; ++kc) {           // K = 8 x 16
            short8 a0h = A0h[kc * 2], a0l = A0l[kc * 2];
            short8 a1h = A1h[kc * 2], a1l = A1l[kc * 2];
            short8 bh = Bhp[kc * 2], bl = Blp[kc * 2];
            acc0 = __builtin_amdgcn_mfma_f32_32x32x16_bf16(a0h, bh, acc0, 0, 0, 0);
            acc0 = __builtin_amdgcn_mfma_f32_32x32x16_bf16(a0l, bh, acc0, 0, 0, 0);
            acc0 = __builtin_amdgcn_mfma_f32_32x32x16_bf16(a0h, bl, acc0, 0, 0, 0);
            acc1 = __builtin_amdgcn_mfma_f32_32x32x16_bf16(a1h, bh, acc1, 0, 0, 0);
            acc1 = __builtin_amdgcn_mfma_f32_32x32x16_bf16(a1l, bh, acc1, 0, 0, 0);
            acc1 = __builtin_amdgcn_mfma_f32_32x32x16_bf16(a1h, bl, acc1, 0, 0, 0);
        }
        int s = s0 + ln;
        unsigned long long sw = selw[b * SS + s];  // coalesced, [b][s] layout
        unsigned long long gw = goodw[b * SS + s];
        float m = NEGF;
#pragma unroll
        for (int r = 0; r < 16; ++r) {
            int row = (r & 3) + 8 * (r >> 2) + 4 * lh;
            float v0 = acc0[r], v1 = acc1[r];
            m = fmaxf(m, ((sw >> row) & 1ull) ? v0 : NEGF);
            m = fmaxf(m, ((sw >> (row + 32)) & 1ull) ? v1 : NEGF);
        }
        m = fmaxf(m, __shfl_xor(m, 32));
        float se = 0.f, sl = 0.f, slg = 0.f;
#pragma unroll
        for (int r = 0; r < 16; ++r) {
            int row = (r & 3) + 8 * (r >> 2) + 4 * lh;
            float v0 = acc0[r], v1 = acc1[r];
            float e0 = ((sw >> row) & 1ull) ? __expf(v0 - m) : 0.f;
            float e1 = ((sw >> (row + 32)) & 1ull) ? __expf(v1 - m) : 0.f;
            se += e0 + e1;
            sl += e0 * v0 + e1 * v1;
            slg += (((gw >> row) & 1ull) ? v0 : 0.f)
                 + (((gw >> (row + 32)) & 1ull) ? v1 : 0.f);
        }
        se += __shfl_xor(se, 32);
        sl += __shfl_xor(sl, 32);
        slg += __shfl_xor(slg, 32);
        if (lh == 0) {
            int o = s * NW + b;                    // TRANSPOSED part: [s][b]
            part[0 * PARTN + o] = m;
            part[1 * PARTN + o] = se;
            part[2 * PARTN + o] = sl;
            part[3 * PARTN + o] = slg;
            part[4 * PARTN + o] = (float)__popcll(sw);
            part[5 * PARTN + o] = (float)__popcll(gw);
        }
    }
}

// ------- per-step merge of 625 block partials (coalesced [s][b] reads) ---------
__global__ __launch_bounds__(64) void k_reduce(const float* __restrict__ part,
                                               float* __restrict__ Aout,
                                               float* __restrict__ Bout,
                                               float* __restrict__ actout) {
    int s = blockIdx.x;
    int t = threadIdx.x;     // 64 threads, one wave
    float m = NEGF, se = 0.f, sl = 0.f, slg = 0.f, np = 0.f, ng = 0.f;
    for (int b = t; b < NW; b += 64) {
        int o = s * NW + b;                        // lanes consecutive
        float m2  = part[0 * PARTN + o];
        float se2 = part[1 * PARTN + o];
        float sl2 = part[2 * PARTN + o];
        slg += part[3 * PARTN + o];
        np  += part[4 * PARTN + o];
        ng  += part[5 * PARTN + o];
        float nm = fmaxf(m, m2);
        float a = __expf(m - nm), a2 = __expf(m2 - nm);
        se = se * a + se2 * a2;
        sl = sl * a + sl2 * a2;
        m = nm;
    }
    for (int off = 32; off > 0; off >>= 1) {
        float m2  = __shfl_xor(m, off);
        float se2 = __shfl_xor(se, off);
        float sl2 = __shfl_xor(sl, off);
        slg += __shfl_xor(slg, off);
        np  += __shfl_xor(np, off);
        ng  += __shfl_xor(ng, off);
        float nm = fmaxf(m, m2);
        float a = __expf(m - nm), a2 = __expf(m2 - nm);
        se = se * a + se2 * a2;
        sl = sl * a + sl2 * a2;
        m = nm;
    }
    if (t == 0) {
        float lse = m + logf(se);
        float nbad = np - ng;
        int active = (ng > 0.5f) && (nbad > 0.5f);
        float ce = (ng * lse - slg) / fmaxf(ng, 1.f);
        float A = (nbad / fmaxf(np, 1.f)) * ce;
        float minus_ent = sl / se - lse;
        float B = ECOEF * (minus_ent / logf(fmaxf(np, 2.0f)));
        Aout[s] = A; Bout[s] = B; actout[s] = active ? 1.f : 0.f;
    }
}

// ---------------- exact sequential discount prefix + final sum -----------------
__global__ __launch_bounds__(64) void k_final(const float* __restrict__ A,
                                              const float* __restrict__ B,
                                              const float* __restrict__ act,
                                              float* __restrict__ out) {
    int lane = threadIdx.x;
    float loss = 0.f;
    int base = 0;
    for (int ch = 0; ch < 8; ++ch) {
        int s = ch * 64 + lane;
        bool a = act[s] > 0.5f;
        unsigned long long bal = __ballot(a);
        unsigned long long ltmask = (lane == 0) ? 0ull : (~0ull >> (64 - lane));
        int pre = __popcll(bal & ltmask);
        if (a) {
            float f = powf(DISCOUNT, (float)(base + pre));
            loss += f * A[s] + B[s];
        }
        base += __popcll(bal);
    }
    for (int off = 32; off > 0; off >>= 1) loss += __shfl_xor(loss, off);
    if (lane == 0) out[0] = loss / fmaxf((float)base, 1.f);
}

extern "C" void kernel_launch(void* const* d_in, const int* in_sizes, int n_in,
                              void* d_out, int out_size, void* d_ws, size_t ws_size,
                              hipStream_t stream) {
    (void)in_sizes; (void)n_in; (void)out_size; (void)ws_size;
    const float* feat    = (const float*)d_in[0];
    const int*   sel     = (const int*)d_in[1];
    const int*   good    = (const int*)d_in[2];
    const int*   sel_idx = (const int*)d_in[3];
    const float* W1      = (const float*)d_in[4];
    const float* b1      = (const float*)d_in[5];
    const float* W2      = (const float*)d_in[6];
    const float* b2      = (const float*)d_in[7];
    const float* init_h  = (const float*)d_in[8];
    const float* init_c  = (const float*)d_in[9];
    const float* Wih     = (const float*)d_in[10];
    const float* Whh     = (const float*)d_in[11];
    const float* bih     = (const float*)d_in[12];
    const float* bhh     = (const float*)d_in[13];
    float* out = (float*)d_out;
    char* ws = (char*)d_ws;

    unsigned short* emb_hi = (unsigned short*)(ws + 20480000);    // 10,240,000 B
    unsigned short* emb_lo = (unsigned short*)(ws + 30720000);    // 10,240,000 B
    float*          P2     = (float*)(ws + 40960000);             //  1,048,576 B
    unsigned short* Hhi    = (unsigned short*)(ws + 42008576);    //    131,072 B
    unsigned short* Hlo    = (unsigned short*)(ws + 42139648);    //    131,072 B
    unsigned long long* selw  = (unsigned long long*)(ws + 42270720);  // 2,560,000 B
    unsigned long long* goodw = (unsigned long long*)(ws + 44830720);  // 2,560,000 B
    float*          part   = (float*)(ws + 47390720);             //  7,680,000 B
    float*          Aarr   = (float*)(ws + 55070720);             //      2,048 B
    float*          Barr   = (float*)(ws + 55072768);             //      2,048 B
    float*          actarr = (float*)(ws + 55074816);             //      2,048 B

    k_pack  <<<1250, 256, 0, stream>>>(sel, good, selw, goodw);
    k_emb   <<<NW, 256, 0, stream>>>(feat, W1, b1, W2, b2, emb_hi, emb_lo);
    k_pgemm <<<64, 256, 0, stream>>>(emb_hi, emb_lo, sel_idx, Wih, bih, bhh, P2);
    k_lstm  <<<1, 512, 0, stream>>>(Whh, P2, init_h, init_c, Hhi, Hlo);
    k_logits<<<NW, 256, 0, stream>>>(emb_hi, emb_lo, Hhi, Hlo, selw, goodw, part);
    k_reduce<<<SS, 64, 0, stream>>>(part, Aarr, Barr, actarr);
    k_final <<<1, 64, 0, stream>>>(Aarr, Barr, actarr, out);
}